// Round 1
// baseline (421.247 us; speedup 1.0000x reference)
//
#include <hip/hip_runtime.h>
#include <stdint.h>

namespace {

constexpr int B = 4, C = 128, H = 256, W = 256;
constexpr int V = H * W;              // 65536
constexpr int E = 163072;             // 32640+32512+32640+32512+32768
constexpr long long CHW = (long long)C * V;
constexpr int ROUNDS = 17;

// Edge enumeration must match reference concat order exactly:
// [L-vert, L-horiz, R-vert, R-horiz, cross]
__device__ __forceinline__ void edge_uv(int e, int& u, int& v) {
  if (e < 32640) {                       // L vertical: h in 0..254, w in 0..127
    int h = e >> 7, w = e & 127;
    u = (h << 8) + w; v = u + 256;
  } else if (e < 65152) {                // L horizontal: h in 0..255, w in 0..126
    int k = e - 32640; int h = k / 127, w = k - h * 127;
    u = (h << 8) + w; v = u + 1;
  } else if (e < 97792) {                // R vertical
    int k = e - 65152; int h = k >> 7, w = k & 127;
    u = (h << 8) + 128 + w; v = u + 256;
  } else if (e < 130304) {               // R horizontal
    int k = e - 97792; int h = k / 127, w = k - h * 127;
    u = (h << 8) + 128 + w; v = u + 1;
  } else {                               // cross: L[h][w] -- R[h][w]
    int k = e - 130304; int h = k >> 7, w = k & 127;
    u = (h << 8) + w; v = u + 128;
  }
}

// Pass 1: per-pixel squared norm (fp64 accumulate) + parent init.
__global__ void k_norm_init(const float* __restrict__ x, double* __restrict__ n2,
                            int* __restrict__ parent) {
  int idx = blockIdx.x * blockDim.x + threadIdx.x;   // exact B*V grid
  int b = idx >> 16, p = idx & (V - 1);
  const float* xb = x + (long long)b * CHW + p;
  double acc = 0.0;
#pragma unroll 8
  for (int c = 0; c < C; ++c) {
    double t = (double)xb[(long long)c * V];
    acc = fma(t, t, acc);
  }
  n2[idx] = acc;
  parent[idx] = p;
}

// Pass 2: per-edge cosine (fp64 dot), round once to fp32, pack sortable key.
__global__ void k_weight(const float* __restrict__ x, const double* __restrict__ n2,
                         unsigned long long* __restrict__ wkey) {
  int idx = blockIdx.x * blockDim.x + threadIdx.x;   // exact B*E grid
  int b = idx / E, e = idx - b * E;
  int u, v; edge_uv(e, u, v);
  const float* xb = x + (long long)b * CHW;
  double dot = 0.0;
#pragma unroll 4
  for (int c = 0; c < C; ++c) {
    long long off = (long long)c * V;
    dot = fma((double)xb[off + u], (double)xb[off + v], dot);
  }
  double denom = fmax(sqrt(n2[(b << 16) + u]) * sqrt(n2[(b << 16) + v]), 1e-8);
  float w = (float)(dot / denom);
  unsigned int bits = __float_as_uint(w);
  if (w == 0.0f) bits = 0u;                          // collapse -0.0 to +0.0
  // order-preserving map fp32 -> uint32
  unsigned int mapped = bits ^ (((int)bits < 0) ? 0xFFFFFFFFu : 0x80000000u);
  wkey[idx] = ((unsigned long long)mapped << 32) | (unsigned int)e;
}

// Round step 1: exact root of each vertex (parent is a forest), init minE.
__global__ void k_root(const int* __restrict__ parent, int* __restrict__ root,
                       unsigned long long* __restrict__ minE) {
  int idx = blockIdx.x * blockDim.x + threadIdx.x;
  int b = idx >> 16, v = idx & (V - 1);
  const int* par = parent + (b << 16);
  int r = v;
  int p = par[r];
  int guard = 0;
  while (p != r && guard < 70000) { r = p; p = par[r]; ++guard; }
  root[idx] = r;
  minE[idx] = ~0ULL;
}

// Round step 2: per-component minimum edge key (lexicographic (w, idx)).
__global__ void k_edgemin(const int* __restrict__ root,
                          const unsigned long long* __restrict__ wkey,
                          unsigned long long* __restrict__ minE) {
  int idx = blockIdx.x * blockDim.x + threadIdx.x;
  int b = idx / E, e = idx - b * E;
  int u, v; edge_uv(e, u, v);
  const int* rt = root + (b << 16);
  int ru = rt[u], rv = rt[v];
  if (ru != rv) {
    unsigned long long k = wkey[idx];
    unsigned long long* mb = minE + (b << 16);
    atomicMin(mb + ru, k);
    atomicMin(mb + rv, k);
  }
}

// Round step 3: select winning edges, hook roots, path-compress everyone.
__global__ void k_hook(const int* __restrict__ root,
                       const unsigned long long* __restrict__ minE,
                       int* __restrict__ parent, float* __restrict__ out) {
  int idx = blockIdx.x * blockDim.x + threadIdx.x;
  int b = idx >> 16, v = idx & (V - 1);
  int r = root[idx];
  int np = r;                       // compression for non-roots; identity for roots
  if (r == v) {
    unsigned long long k = minE[idx];
    if (k != ~0ULL) {
      int e = (int)(k & 0xFFFFFFFFu);
      int eu, ev; edge_uv(e, eu, ev);
      const int* rt = root + (b << 16);
      int ru = rt[eu], rv = rt[ev];
      out[b * E + e] = 1.0f;        // winner (idempotent if both sides pick it)
      np = (v == ru) ? rv : ru;     // hook to the other component's root
    }
  }
  parent[idx] = np;
}

// Round step 4: break 2-cycles (mutual hooks): smaller id becomes root.
__global__ void k_break(int* __restrict__ parent) {
  int idx = blockIdx.x * blockDim.x + threadIdx.x;
  int b = idx >> 16, v = idx & (V - 1);
  int* par = parent + (b << 16);
  int p = par[v];
  if (v < p && par[p] == v) par[v] = v;
}

} // namespace

extern "C" void kernel_launch(void* const* d_in, const int* in_sizes, int n_in,
                              void* d_out, int out_size, void* d_ws, size_t ws_size,
                              hipStream_t stream) {
  const float* x = (const float*)d_in[0];
  float* out = (float*)d_out;

  char* ws = (char*)d_ws;
  size_t off = 0;
  auto alloc = [&](size_t bytes) {
    void* p = (void*)(ws + off);
    off += (bytes + 255) & ~(size_t)255;
    return p;
  };
  int* parent = (int*)alloc((size_t)B * V * sizeof(int));                      // 1 MB
  int* root   = (int*)alloc((size_t)B * V * sizeof(int));                      // 1 MB
  unsigned long long* minE = (unsigned long long*)alloc((size_t)B * V * 8);    // 2 MB
  double* n2  = (double*)alloc((size_t)B * V * sizeof(double));                // 2 MB
  unsigned long long* wkey = (unsigned long long*)alloc((size_t)B * E * 8);    // ~5 MB

  // Output mask starts at 0; winners set 1.0f. Re-done every call (deterministic).
  hipMemsetAsync(d_out, 0, (size_t)B * E * sizeof(float), stream);

  k_norm_init<<<(B * V) / 256, 256, 0, stream>>>(x, n2, parent);
  k_weight<<<(B * E) / 256, 256, 0, stream>>>(x, n2, wkey);

  for (int r = 0; r < ROUNDS; ++r) {
    k_root   <<<(B * V) / 256, 256, 0, stream>>>(parent, root, minE);
    k_edgemin<<<(B * E) / 256, 256, 0, stream>>>(root, wkey, minE);
    k_hook   <<<(B * V) / 256, 256, 0, stream>>>(root, minE, parent, out);
    k_break  <<<(B * V) / 256, 256, 0, stream>>>(parent);
  }
}